// Round 1
// baseline (1170.895 us; speedup 1.0000x reference)
//
#include <hip/hip_runtime.h>
#include <math.h>

#define DIM 1024
#define SEQ 4096
#define HEADS 8
#define DHEAD 64
#define DINNER 512   // HEADS*DHEAD
#define QKVW 1536    // 3*DINNER

// ---------------- RMSNorm: normed = x / max(||x||,1e-12) * 32 * gamma ----------------
__global__ __launch_bounds__(256) void rmsnorm_kernel(const float* __restrict__ x,
                                                      const float* __restrict__ gamma,
                                                      float* __restrict__ out) {
    __shared__ float red[4];
    const int r = blockIdx.x;
    const int t = threadIdx.x;
    const float* xr = x + (size_t)r * DIM;
    float v[4];
    float ss = 0.f;
#pragma unroll
    for (int i = 0; i < 4; ++i) {
        v[i] = xr[t + i * 256];
        ss += v[i] * v[i];
    }
#pragma unroll
    for (int off = 32; off >= 1; off >>= 1) ss += __shfl_xor(ss, off, 64);
    if ((t & 63) == 0) red[t >> 6] = ss;
    __syncthreads();
    float tot = red[0] + red[1] + red[2] + red[3];
    float scale = 32.0f / fmaxf(sqrtf(tot), 1e-12f);
#pragma unroll
    for (int i = 0; i < 4; ++i) {
        int c = t + i * 256;
        out[(size_t)r * DIM + c] = v[i] * scale * gamma[c];
    }
}

// ---------------- fp32 tiled GEMM: C[M,N] = A[M,K] @ B[K,N], all row-major ----------------
// BM=BN=64, BK=16, 256 threads, 4x4 micro-tile per thread. Dims must divide evenly.
__global__ __launch_bounds__(256) void gemm_f32_kernel(const float* __restrict__ A,
                                                       const float* __restrict__ B,
                                                       float* __restrict__ C,
                                                       int M, int N, int K) {
    __shared__ float As[16][65];
    __shared__ float Bs[16][65];
    const int t = threadIdx.x;
    const int bm = blockIdx.y * 64;
    const int bn = blockIdx.x * 64;
    const int ty = t >> 4, tx = t & 15;
    float acc[4][4] = {};
    for (int k0 = 0; k0 < K; k0 += 16) {
#pragma unroll
        for (int i = 0; i < 4; ++i) {
            int e = t + i * 256;
            int ar = e >> 4, ac = e & 15;
            As[ac][ar] = A[(size_t)(bm + ar) * K + k0 + ac];
        }
#pragma unroll
        for (int i = 0; i < 4; ++i) {
            int e = t + i * 256;
            int br = e >> 6, bc = e & 63;
            Bs[br][bc] = B[(size_t)(k0 + br) * N + bn + bc];
        }
        __syncthreads();
#pragma unroll
        for (int kk = 0; kk < 16; ++kk) {
            float a[4], b[4];
#pragma unroll
            for (int i = 0; i < 4; ++i) a[i] = As[kk][ty * 4 + i];
#pragma unroll
            for (int j = 0; j < 4; ++j) b[j] = Bs[kk][tx * 4 + j];
#pragma unroll
            for (int i = 0; i < 4; ++i)
#pragma unroll
                for (int j = 0; j < 4; ++j) acc[i][j] += a[i] * b[j];
        }
        __syncthreads();
    }
#pragma unroll
    for (int i = 0; i < 4; ++i)
#pragma unroll
        for (int j = 0; j < 4; ++j)
            C[(size_t)(bm + ty * 4 + i) * N + bn + tx * 4 + j] = acc[i][j];
}

// ---------------- causal flash attention, fp32 ----------------
// qkv: [SEQ][1536] with q at col h*64, k at 512+h*64, v at 1024+h*64.
// out: [SEQ][512] at col h*64. q is pre-scaled by sqrt(d)=8 (faithful to ref).
// Block = 256 threads handles one (qtile of 64 rows, head). Online softmax.
__global__ __launch_bounds__(256) void attn_kernel(const float* __restrict__ qkv,
                                                   float* __restrict__ out) {
    __shared__ float Qs[64][65];
    __shared__ float Ks[64][65];   // reused as P after scores are consumed
    __shared__ float Vs[64][65];
    const int t = threadIdx.x;
    const int qt = blockIdx.x;
    const int h = blockIdx.y;
    const int ty = t >> 4, tx = t & 15;

#pragma unroll
    for (int i = 0; i < 16; ++i) {
        int e = t + i * 256;
        int r = e >> 6, c = e & 63;
        Qs[r][c] = qkv[(size_t)(qt * 64 + r) * QKVW + h * 64 + c] * 8.0f;
    }

    float m[4], l[4], o[4][4];
#pragma unroll
    for (int i = 0; i < 4; ++i) {
        m[i] = -1e30f;
        l[i] = 0.f;
#pragma unroll
        for (int j = 0; j < 4; ++j) o[i][j] = 0.f;
    }

    for (int kt = 0; kt <= qt; ++kt) {
        __syncthreads();  // protect Ks/Vs from previous iteration's readers
#pragma unroll
        for (int i = 0; i < 16; ++i) {
            int e = t + i * 256;
            int r = e >> 6, c = e & 63;
            size_t row = (size_t)(kt * 64 + r) * QKVW + h * 64 + c;
            Ks[r][c] = qkv[row + 512];
            Vs[r][c] = qkv[row + 1024];
        }
        __syncthreads();

        float s[4][4];
#pragma unroll
        for (int i = 0; i < 4; ++i)
#pragma unroll
            for (int j = 0; j < 4; ++j) s[i][j] = 0.f;
#pragma unroll
        for (int d = 0; d < 64; ++d) {
            float a[4], b[4];
#pragma unroll
            for (int i = 0; i < 4; ++i) a[i] = Qs[ty * 4 + i][d];
#pragma unroll
            for (int j = 0; j < 4; ++j) b[j] = Ks[tx * 4 + j][d];
#pragma unroll
            for (int i = 0; i < 4; ++i)
#pragma unroll
                for (int j = 0; j < 4; ++j) s[i][j] += a[i] * b[j];
        }
        if (kt == qt) {
#pragma unroll
            for (int i = 0; i < 4; ++i)
#pragma unroll
                for (int j = 0; j < 4; ++j)
                    if (tx * 4 + j > ty * 4 + i) s[i][j] = -1e30f;
        }

        // online softmax per row (16 tx threads share a row -> shfl over width 16)
#pragma unroll
        for (int i = 0; i < 4; ++i) {
            float rm = fmaxf(fmaxf(s[i][0], s[i][1]), fmaxf(s[i][2], s[i][3]));
#pragma unroll
            for (int off = 8; off >= 1; off >>= 1) rm = fmaxf(rm, __shfl_xor(rm, off, 16));
            float mn = fmaxf(m[i], rm);
            float alpha = __expf(m[i] - mn);
            float rs = 0.f;
#pragma unroll
            for (int j = 0; j < 4; ++j) {
                s[i][j] = __expf(s[i][j] - mn);
                rs += s[i][j];
            }
#pragma unroll
            for (int off = 8; off >= 1; off >>= 1) rs += __shfl_xor(rs, off, 16);
            l[i] = l[i] * alpha + rs;
            m[i] = mn;
#pragma unroll
            for (int j = 0; j < 4; ++j) o[i][j] *= alpha;
        }

        __syncthreads();  // everyone done reading Ks (scores)
        // write P into Ks storage
#pragma unroll
        for (int i = 0; i < 4; ++i)
#pragma unroll
            for (int j = 0; j < 4; ++j) Ks[ty * 4 + i][tx * 4 + j] = s[i][j];
        __syncthreads();

        // O += P @ V
#pragma unroll
        for (int n = 0; n < 64; ++n) {
            float p[4], v[4];
#pragma unroll
            for (int i = 0; i < 4; ++i) p[i] = Ks[ty * 4 + i][n];
#pragma unroll
            for (int j = 0; j < 4; ++j) v[j] = Vs[n][tx * 4 + j];
#pragma unroll
            for (int i = 0; i < 4; ++i)
#pragma unroll
                for (int j = 0; j < 4; ++j) o[i][j] += p[i] * v[j];
        }
    }

#pragma unroll
    for (int i = 0; i < 4; ++i) {
        float inv = 1.0f / l[i];
#pragma unroll
        for (int j = 0; j < 4; ++j)
            out[(size_t)(qt * 64 + ty * 4 + i) * DINNER + h * 64 + tx * 4 + j] =
                o[i][j] * inv;
    }
}

extern "C" void kernel_launch(void* const* d_in, const int* in_sizes, int n_in,
                              void* d_out, int out_size, void* d_ws, size_t ws_size,
                              hipStream_t stream) {
    const float* x     = (const float*)d_in[0];
    const float* gamma = (const float*)d_in[1];
    const float* w_qkv = (const float*)d_in[2];
    const float* w_out = (const float*)d_in[3];
    float* out = (float*)d_out;

    float* qkv  = (float*)d_ws;                       // SEQ*1536 floats = 24 MB
    float* atto = qkv + (size_t)SEQ * QKVW;           // SEQ*512 floats  = 8 MB
    size_t need_all = ((size_t)SEQ * QKVW + (size_t)SEQ * DINNER + (size_t)SEQ * DIM) * 4;
    // normed goes in ws if it fits, else reuse d_out (fully overwritten at the end)
    float* normed = (ws_size >= need_all) ? (atto + (size_t)SEQ * DINNER) : out;

    rmsnorm_kernel<<<SEQ, 256, 0, stream>>>(x, gamma, normed);
    gemm_f32_kernel<<<dim3(QKVW / 64, SEQ / 64), 256, 0, stream>>>(normed, w_qkv, qkv,
                                                                   SEQ, QKVW, DIM);
    attn_kernel<<<dim3(SEQ / 64, HEADS), 256, 0, stream>>>(qkv, atto);
    gemm_f32_kernel<<<dim3(DIM / 64, SEQ / 64), 256, 0, stream>>>(atto, w_out, out,
                                                                  SEQ, DIM, DINNER);
}

// Round 2
// 295.409 us; speedup vs baseline: 3.9636x; 3.9636x over previous
//
#include <hip/hip_runtime.h>
#include <math.h>

#define SEQ 4096
#define DIM 1024
#define HEADS 8
#define DINNER 512
#define QKVW 1536
#define PAD 80   // LDS row stride in bf16 elems: 160B = 10 x 16B granules, balanced banks

typedef unsigned short u16;
typedef __attribute__((ext_vector_type(8))) short s8v;   // 8 bf16 (4 VGPRs)
typedef __attribute__((ext_vector_type(4))) float f4v;   // 4 fp32 acc
#define MFMA(a, b, c) __builtin_amdgcn_mfma_f32_16x16x32_bf16(a, b, c, 0, 0, 0)

__device__ __forceinline__ u16 f2bf(float f) {
    unsigned u = __float_as_uint(f);
    u += 0x7fff + ((u >> 16) & 1);   // RNE
    return (u16)(u >> 16);
}
__device__ __forceinline__ float bf2f(u16 b) { return __uint_as_float(((unsigned)b) << 16); }

// ---------- RMSNorm -> split bf16 (hi, lo) ----------
__global__ __launch_bounds__(256) void rmsnorm_split(const float* __restrict__ x,
                                                     const float* __restrict__ gamma,
                                                     u16* __restrict__ hi,
                                                     u16* __restrict__ lo) {
    __shared__ float red[4];
    const int row = blockIdx.x, t = threadIdx.x;
    const float* xr = x + (size_t)row * DIM;
    float v[4];
    float ss = 0.f;
#pragma unroll
    for (int i = 0; i < 4; ++i) { v[i] = xr[t + i * 256]; ss += v[i] * v[i]; }
#pragma unroll
    for (int off = 32; off >= 1; off >>= 1) ss += __shfl_xor(ss, off, 64);
    if ((t & 63) == 0) red[t >> 6] = ss;
    __syncthreads();
    float scale = 32.0f / fmaxf(sqrtf(red[0] + red[1] + red[2] + red[3]), 1e-12f);
#pragma unroll
    for (int i = 0; i < 4; ++i) {
        int c = t + i * 256;
        float y = v[i] * scale * gamma[c];
        u16 h = f2bf(y);
        hi[(size_t)row * DIM + c] = h;
        lo[(size_t)row * DIM + c] = f2bf(y - bf2f(h));
    }
}

// ---------- transpose fp32 [R][C] -> bf16 hi/lo [C][R] ----------
__global__ __launch_bounds__(256) void transpose_split(const float* __restrict__ in,
                                                       u16* __restrict__ hi,
                                                       u16* __restrict__ lo,
                                                       int R, int C, int want_lo) {
    __shared__ float tile[64][65];
    const int c0 = blockIdx.x * 64, r0 = blockIdx.y * 64;
    const int t = threadIdx.x, col = t & 63, rb = t >> 6;
#pragma unroll
    for (int j = 0; j < 16; ++j)
        tile[rb + j * 4][col] = in[(size_t)(r0 + rb + j * 4) * C + c0 + col];
    __syncthreads();
#pragma unroll
    for (int j = 0; j < 16; ++j) {
        int cc = rb + j * 4;
        float v = tile[col][cc];
        size_t oi = (size_t)(c0 + cc) * R + r0 + col;
        u16 h = f2bf(v);
        hi[oi] = h;
        if (want_lo) lo[oi] = f2bf(v - bf2f(h));
    }
}

// ---------- QKV GEMM, split-bf16 (3 MFMAs), fused split/scale epilogue ----------
// A: normed hi/lo [4096][1024], B: w_qkv^T hi/lo [1536][1024].
// cols 0..511 -> q*8 split into qh/ql [n][512]; 512..1023 -> kh/kl; 1024.. -> vt[dinner][n] bf16
__global__ __launch_bounds__(256) void gemm_qkv_split(
    const u16* __restrict__ Ah, const u16* __restrict__ Al,
    const u16* __restrict__ Bh, const u16* __restrict__ Bl,
    u16* __restrict__ qh, u16* __restrict__ ql,
    u16* __restrict__ kh, u16* __restrict__ kl, u16* __restrict__ vtp) {
    __shared__ u16 Ash[64 * PAD], Asl[64 * PAD], Bsh[64 * PAD], Bsl[64 * PAD];
    const int t = threadIdx.x;
    const int bn = blockIdx.x * 64, bm = blockIdx.y * 64;
    const int w = t >> 6, lane = t & 63, m = lane & 15, q = lane >> 4;
    f4v acc[4] = {{0.f, 0.f, 0.f, 0.f}, {0.f, 0.f, 0.f, 0.f},
                  {0.f, 0.f, 0.f, 0.f}, {0.f, 0.f, 0.f, 0.f}};
    for (int k0 = 0; k0 < DIM; k0 += 64) {
        __syncthreads();
#pragma unroll
        for (int i = 0; i < 2; ++i) {
            int c = t + i * 256, row = c >> 3, ch = (c & 7) * 8;
            *(uint4*)&Ash[row * PAD + ch] = *(const uint4*)&Ah[(size_t)(bm + row) * DIM + k0 + ch];
            *(uint4*)&Asl[row * PAD + ch] = *(const uint4*)&Al[(size_t)(bm + row) * DIM + k0 + ch];
            *(uint4*)&Bsh[row * PAD + ch] = *(const uint4*)&Bh[(size_t)(bn + row) * DIM + k0 + ch];
            *(uint4*)&Bsl[row * PAD + ch] = *(const uint4*)&Bl[(size_t)(bn + row) * DIM + k0 + ch];
        }
        __syncthreads();
#pragma unroll
        for (int kk = 0; kk < 64; kk += 32) {
            s8v ah = *(const s8v*)&Ash[(w * 16 + m) * PAD + kk + q * 8];
            s8v al = *(const s8v*)&Asl[(w * 16 + m) * PAD + kk + q * 8];
#pragma unroll
            for (int ct = 0; ct < 4; ++ct) {
                s8v bh = *(const s8v*)&Bsh[(ct * 16 + m) * PAD + kk + q * 8];
                s8v bl = *(const s8v*)&Bsl[(ct * 16 + m) * PAD + kk + q * 8];
                acc[ct] = MFMA(ah, bh, acc[ct]);
                acc[ct] = MFMA(al, bh, acc[ct]);
                acc[ct] = MFMA(ah, bl, acc[ct]);
            }
        }
    }
    const int region = bn >> 9;   // uniform per block
#pragma unroll
    for (int ct = 0; ct < 4; ++ct) {
#pragma unroll
        for (int r = 0; r < 4; ++r) {
            int gr = bm + w * 16 + q * 4 + r;
            int gc = bn + ct * 16 + m;
            float v = acc[ct][r];
            if (region == 0) {
                v *= 8.0f;   // q * sqrt(d), faithful to reference
                u16 h = f2bf(v);
                qh[(size_t)gr * DINNER + gc] = h;
                ql[(size_t)gr * DINNER + gc] = f2bf(v - bf2f(h));
            } else if (region == 1) {
                u16 h = f2bf(v);
                kh[(size_t)gr * DINNER + (gc - 512)] = h;
                kl[(size_t)gr * DINNER + (gc - 512)] = f2bf(v - bf2f(h));
            } else {
                vtp[(size_t)(gc - 1024) * SEQ + gr] = f2bf(v);
            }
        }
    }
}

// ---------- flash attention, MFMA, split-bf16 QK^T ----------
// qh/ql/kh/kl: [n][512] per-head cols h*64..; vt: [h*64+d][n]. out atto bf16 [n][512].
__global__ __launch_bounds__(256) void attn_mfma(
    const u16* __restrict__ qh, const u16* __restrict__ ql,
    const u16* __restrict__ kh, const u16* __restrict__ kl,
    const u16* __restrict__ vt, u16* __restrict__ atto) {
    __shared__ u16 Qh[64 * PAD], Ql[64 * PAD], KP[64 * PAD], Kl[64 * PAD], Vt[64 * PAD];
    const int t = threadIdx.x;
    const int qt = blockIdx.x, h = blockIdx.y;
    const int w = t >> 6, lane = t & 63, m = lane & 15, q = lane >> 4;

#pragma unroll
    for (int i = 0; i < 2; ++i) {
        int c = t + i * 256, row = c >> 3, ch = (c & 7) * 8;
        *(uint4*)&Qh[row * PAD + ch] =
            *(const uint4*)&qh[(size_t)(qt * 64 + row) * DINNER + h * 64 + ch];
        *(uint4*)&Ql[row * PAD + ch] =
            *(const uint4*)&ql[(size_t)(qt * 64 + row) * DINNER + h * 64 + ch];
    }

    f4v o[4] = {{0.f, 0.f, 0.f, 0.f}, {0.f, 0.f, 0.f, 0.f},
                {0.f, 0.f, 0.f, 0.f}, {0.f, 0.f, 0.f, 0.f}};
    float mi[4] = {-1e30f, -1e30f, -1e30f, -1e30f};
    float li[4] = {0.f, 0.f, 0.f, 0.f};

    for (int kt = 0; kt <= qt; ++kt) {
        __syncthreads();   // prior iteration's P/Vt consumers done
#pragma unroll
        for (int i = 0; i < 2; ++i) {
            int c = t + i * 256, row = c >> 3, ch = (c & 7) * 8;
            *(uint4*)&KP[row * PAD + ch] =
                *(const uint4*)&kh[(size_t)(kt * 64 + row) * DINNER + h * 64 + ch];
            *(uint4*)&Kl[row * PAD + ch] =
                *(const uint4*)&kl[(size_t)(kt * 64 + row) * DINNER + h * 64 + ch];
            *(uint4*)&Vt[row * PAD + ch] =
                *(const uint4*)&vt[(size_t)(h * 64 + row) * SEQ + kt * 64 + ch];
        }
        __syncthreads();

        // S strip (16 rows x 64 cols) per wave, split QK^T: 3 MFMAs per 16x16x32
        f4v s[4] = {{0.f, 0.f, 0.f, 0.f}, {0.f, 0.f, 0.f, 0.f},
                    {0.f, 0.f, 0.f, 0.f}, {0.f, 0.f, 0.f, 0.f}};
#pragma unroll
        for (int kk = 0; kk < 64; kk += 32) {
            s8v ah = *(const s8v*)&Qh[(w * 16 + m) * PAD + kk + q * 8];
            s8v al = *(const s8v*)&Ql[(w * 16 + m) * PAD + kk + q * 8];
#pragma unroll
            for (int ct = 0; ct < 4; ++ct) {
                s8v bh = *(const s8v*)&KP[(ct * 16 + m) * PAD + kk + q * 8];
                s8v bl = *(const s8v*)&Kl[(ct * 16 + m) * PAD + kk + q * 8];
                s[ct] = MFMA(ah, bh, s[ct]);
                s[ct] = MFMA(al, bh, s[ct]);
                s[ct] = MFMA(ah, bl, s[ct]);
            }
        }
        if (kt == qt) {   // causal: mask col > row (tile-local, same tile offset)
#pragma unroll
            for (int ct = 0; ct < 4; ++ct)
#pragma unroll
                for (int r = 0; r < 4; ++r)
                    if (ct * 16 + m > w * 16 + q * 4 + r) s[ct][r] = -1e30f;
        }

        // online softmax: row = w*16 + q*4 + r lives on the 16-lane group (lane>>4)==q
        float alpha[4];
#pragma unroll
        for (int r = 0; r < 4; ++r) {
            float rm = fmaxf(fmaxf(s[0][r], s[1][r]), fmaxf(s[2][r], s[3][r]));
#pragma unroll
            for (int off = 8; off >= 1; off >>= 1) rm = fmaxf(rm, __shfl_xor(rm, off, 64));
            float mn = fmaxf(mi[r], rm);
            alpha[r] = __expf(mi[r] - mn);
            mi[r] = mn;
            float rs = 0.f;
#pragma unroll
            for (int ct = 0; ct < 4; ++ct) {
                s[ct][r] = __expf(s[ct][r] - mn);
                rs += s[ct][r];
            }
#pragma unroll
            for (int off = 8; off >= 1; off >>= 1) rs += __shfl_xor(rs, off, 64);
            li[r] = li[r] * alpha[r] + rs;
        }

        __syncthreads();   // all waves done reading KP as K-hi before P overwrite
#pragma unroll
        for (int ct = 0; ct < 4; ++ct)
#pragma unroll
            for (int r = 0; r < 4; ++r) {
                KP[(w * 16 + q * 4 + r) * PAD + ct * 16 + m] = f2bf(s[ct][r]);
                o[ct][r] *= alpha[r];
            }
        // PV: each wave reads only its own P rows (w*16..w*16+15) -> no barrier needed
#pragma unroll
        for (int kk = 0; kk < 64; kk += 32) {
            s8v ap = *(const s8v*)&KP[(w * 16 + m) * PAD + kk + q * 8];
#pragma unroll
            for (int ct = 0; ct < 4; ++ct) {
                s8v bv = *(const s8v*)&Vt[(ct * 16 + m) * PAD + kk + q * 8];
                o[ct] = MFMA(ap, bv, o[ct]);
            }
        }
    }

#pragma unroll
    for (int r = 0; r < 4; ++r) {
        float inv = 1.0f / li[r];
#pragma unroll
        for (int ct = 0; ct < 4; ++ct)
            atto[(size_t)(qt * 64 + w * 16 + q * 4 + r) * DINNER + h * 64 + ct * 16 + m] =
                f2bf(o[ct][r] * inv);
    }
}

// ---------- out projection: atto bf16 [4096][512] @ w_out^T bf16 [1024][512] -> fp32 ----------
__global__ __launch_bounds__(256) void gemm_out_bf16(const u16* __restrict__ A,
                                                     const u16* __restrict__ Bt,
                                                     float* __restrict__ C) {
    __shared__ u16 As[64 * PAD], Bs[64 * PAD];
    const int t = threadIdx.x;
    const int bn = blockIdx.x * 64, bm = blockIdx.y * 64;
    const int w = t >> 6, lane = t & 63, m = lane & 15, q = lane >> 4;
    f4v acc[4] = {{0.f, 0.f, 0.f, 0.f}, {0.f, 0.f, 0.f, 0.f},
                  {0.f, 0.f, 0.f, 0.f}, {0.f, 0.f, 0.f, 0.f}};
    for (int k0 = 0; k0 < DINNER; k0 += 64) {
        __syncthreads();
#pragma unroll
        for (int i = 0; i < 2; ++i) {
            int c = t + i * 256, row = c >> 3, ch = (c & 7) * 8;
            *(uint4*)&As[row * PAD + ch] = *(const uint4*)&A[(size_t)(bm + row) * DINNER + k0 + ch];
            *(uint4*)&Bs[row * PAD + ch] = *(const uint4*)&Bt[(size_t)(bn + row) * DINNER + k0 + ch];
        }
        __syncthreads();
#pragma unroll
        for (int kk = 0; kk < 64; kk += 32) {
            s8v a = *(const s8v*)&As[(w * 16 + m) * PAD + kk + q * 8];
#pragma unroll
            for (int ct = 0; ct < 4; ++ct) {
                s8v b = *(const s8v*)&Bs[(ct * 16 + m) * PAD + kk + q * 8];
                acc[ct] = MFMA(a, b, acc[ct]);
            }
        }
    }
#pragma unroll
    for (int ct = 0; ct < 4; ++ct)
#pragma unroll
        for (int r = 0; r < 4; ++r)
            C[(size_t)(bm + w * 16 + q * 4 + r) * DIM + bn + ct * 16 + m] = acc[ct][r];
}

extern "C" void kernel_launch(void* const* d_in, const int* in_sizes, int n_in,
                              void* d_out, int out_size, void* d_ws, size_t ws_size,
                              hipStream_t stream) {
    const float* x     = (const float*)d_in[0];
    const float* gamma = (const float*)d_in[1];
    const float* w_qkv = (const float*)d_in[2];
    const float* w_out = (const float*)d_in[3];
    float* out = (float*)d_out;

    // normed hi/lo live in d_out (2 * 4096*1024 * 2B == 4096*1024 * 4B, exact fit;
    // fully consumed by gemm_qkv before gemm_out overwrites d_out)
    u16* nh = (u16*)d_out;
    u16* nl = nh + (size_t)SEQ * DIM;

    u16* p = (u16*)d_ws;
    u16* wqt_h = p; p += (size_t)QKVW * DIM;
    u16* wqt_l = p; p += (size_t)QKVW * DIM;
    u16* wot   = p; p += (size_t)DIM * DINNER;
    u16* qh = p; p += (size_t)SEQ * DINNER;
    u16* ql = p; p += (size_t)SEQ * DINNER;
    u16* kh = p; p += (size_t)SEQ * DINNER;
    u16* kl = p; p += (size_t)SEQ * DINNER;
    u16* vt = p; p += (size_t)DINNER * SEQ;
    u16* atto = p; p += (size_t)SEQ * DINNER;

    transpose_split<<<dim3(QKVW / 64, DIM / 64), 256, 0, stream>>>(w_qkv, wqt_h, wqt_l,
                                                                   DIM, QKVW, 1);
    transpose_split<<<dim3(DIM / 64, DINNER / 64), 256, 0, stream>>>(w_out, wot, nullptr,
                                                                     DINNER, DIM, 0);
    rmsnorm_split<<<SEQ, 256, 0, stream>>>(x, gamma, nh, nl);
    gemm_qkv_split<<<dim3(QKVW / 64, SEQ / 64), 256, 0, stream>>>(nh, nl, wqt_h, wqt_l,
                                                                  qh, ql, kh, kl, vt);
    attn_mfma<<<dim3(SEQ / 64, HEADS), 256, 0, stream>>>(qh, ql, kh, kl, vt, atto);
    gemm_out_bf16<<<dim3(DIM / 64, SEQ / 64), 256, 0, stream>>>(atto, wot, out);
}